// Round 3
// 217.391 us; speedup vs baseline: 1.0729x; 1.0729x over previous
//
#include <hip/hip_runtime.h>

typedef unsigned short u16;
typedef unsigned int u32;
typedef unsigned long long u64;
typedef __attribute__((ext_vector_type(8))) short bf8v;   // 8 bf16 as raw shorts (4 VGPRs)
typedef __attribute__((ext_vector_type(4))) float f32x4;
typedef __attribute__((ext_vector_type(4))) u32 u32x4;
typedef __attribute__((ext_vector_type(2))) __fp16 fp16x2;

#define S_   1024
#define POS_ 2048

__device__ __forceinline__ float b2f(u16 h){
  union { float f; unsigned u; } x; x.u = ((unsigned)h) << 16; return x.f;
}
__device__ __forceinline__ u16 f2b(float f){
  union { float f; unsigned u; } x; x.f = f;
  unsigned u = x.u;
  return (u16)((u + 0x7fffu + ((u >> 16) & 1u)) >> 16);
}
__device__ __forceinline__ u16 f2bt(float f){     // truncate (cheap)
  union { float f; unsigned u; } x; x.f = f;
  return (u16)(x.u >> 16);
}

#define GLDS16(g, l) __builtin_amdgcn_global_load_lds( \
    (const __attribute__((address_space(1))) unsigned int*)(g), \
    (__attribute__((address_space(3))) unsigned int*)(l), 16, 0, 0)

// ---------------- fused prep: weight transposes + transposed mask bitmask + fp32->bf16 convert ----------------
// blocks [0,2304): transpose q/kv/r->wqkv, wo->wout (fp32 -> bf16)
// blocks [2304,2816): mask -> TRANSPOSED u32 bitmask: word (b,it,kt,key) holds bits r=0..31 for
//   rows i = it*32+r at key kt*64+key: mbT[((b*32+it)*16+kt)*64 + key]. block 2304 zeroes zp.
// blocks [2816,7424): hidden/pos fp32 -> bf16 (big path only)
__global__ __launch_bounds__(256) void prep(const float* __restrict__ q, const float* __restrict__ kv,
                                            const float* __restrict__ r, const float* __restrict__ wo,
                                            u16* __restrict__ wqkv, u16* __restrict__ wout,
                                            const float* __restrict__ mask, u32* __restrict__ mbT,
                                            u16* __restrict__ zp,
                                            const float* __restrict__ hidden, const float* __restrict__ pos,
                                            u16* __restrict__ hb, u16* __restrict__ pb){
  int blk = blockIdx.x, tid = threadIdx.x;
  if (blk < 2304){
    __shared__ u16 t[32][33];
    int z = blk / 576, rem = blk % 576;
    const float* src; u16* dst;
    if (z == 0){ src = q;  dst = wqkv; }
    else if (z == 1){ src = kv; dst = wqkv + 768*768; }
    else if (z == 2){ src = r;  dst = wqkv + 2*768*768; }
    else { src = wo; dst = wout; }
    int gx = (rem % 24)*32, gy = (rem / 24)*32;
    int tx = tid & 31, ty = tid >> 5;
    #pragma unroll
    for (int k = 0; k < 4; ++k)
      t[ty + 8*k][tx] = f2b(src[(gy + ty + 8*k)*768 + gx + tx]);
    __syncthreads();
    #pragma unroll
    for (int k = 0; k < 4; ++k)
      dst[(gx + ty + 8*k)*768 + gy + tx] = t[tx][ty + 8*k];
  } else if (blk < 2816){
    int widx = (blk - 2304)*4 + (tid >> 6);      // ((b*32+it)*16+kt) in [0,2048)
    int lane = tid & 63;
    int kt = widx & 15, bi = widx >> 4;          // bi = b*32+it
    const float* mrow = mask + (size_t)bi*32*1024 + kt*64 + lane;
    u32 m = 0;
    #pragma unroll
    for (int rr = 0; rr < 32; ++rr)
      m |= (mrow[(size_t)rr*1024] != 0.0f ? 1u : 0u) << rr;
    mbT[(size_t)widx*64 + lane] = m;
    if (blk == 2304 && tid < 8) zp[tid] = 0;
  } else {
    size_t i = ((size_t)(blk - 2816)*256 + tid)*8;
    const float* s; u16* d;
    if (i < 3145728){ s = hidden + i; d = hb + i; }
    else { s = pos + (i - 3145728); d = pb + (i - 3145728); }
    f32x4 x0 = *(const f32x4*)s, x1 = *(const f32x4*)(s + 4);
    bf8v t;
    #pragma unroll
    for (int j = 0; j < 4; ++j){ t[j] = f2b(x0[j]); t[4+j] = f2b(x1[j]); }
    *(bf8v*)d = t;
  }
}

// ---------------- MFMA bf16 GEMM core: C[M,N] = A[M,768] @ Bt[N,768]^T ----------------
// 128x128 tile, 4 waves (2x2 of 64x64), BK=32. Unpadded LDS [128][32] with XOR k-chunk
// swizzle; B (and bf16-A) staged via global_load_lds width=16.
// MODE bit1: A bf16 (GLDS) else fp32 (VGPR truncate-pack). Stores bf16 C.
template<int MODE>
__device__ __forceinline__ void gemm_core(const void* Av, int lda, const u16* Bt,
                                          u16* Cv, int ldc,
                                          int bm, int bn,
                                          u16 (*As)[32], u16 (*Bs)[32]){
  int tid = threadIdx.x;
  int lane = tid & 63, rg = tid >> 6;
  int quad = lane >> 4, l15 = lane & 15;
  int wm = rg >> 1, wn = rg & 1;
  int poff = (quad ^ ((l15 >> 1) & 3)) * 8;
  f32x4 acc[4][4];
  #pragma unroll
  for (int i = 0; i < 4; ++i)
    #pragma unroll
    for (int j = 0; j < 4; ++j)
      acc[i][j] = (f32x4){0.f,0.f,0.f,0.f};

  for (int kt = 0; kt < 24; ++kt){
    int k0 = kt*32;
    if (kt) __syncthreads();
    #pragma unroll
    for (int t = 0; t < 2; ++t){
      int m = (rg*2 + t)*16 + (lane >> 2);
      int g = ((lane & 3) ^ ((m >> 1) & 3)) * 8;
      GLDS16(&Bt[(size_t)(bn*128 + m)*768 + k0 + g], &Bs[m][(lane & 3)*8]);
    }
    if (MODE & 2){
      #pragma unroll
      for (int t = 0; t < 2; ++t){
        int m = (rg*2 + t)*16 + (lane >> 2);
        int g = ((lane & 3) ^ ((m >> 1) & 3)) * 8;
        GLDS16(&((const u16*)Av)[(size_t)(bm*128 + m)*lda + k0 + g], &As[m][(lane & 3)*8]);
      }
    } else {
      #pragma unroll
      for (int e = 0; e < 2; ++e){
        int v = tid + 256*e;
        int m = v >> 2, c = v & 3;
        const u32* ap = (const u32*)Av + (size_t)(bm*128 + m)*lda + k0 + c*8;
        u32x4 a0 = *(const u32x4*)ap;
        u32x4 a1 = *(const u32x4*)(ap + 4);
        u32x4 pk;
        pk[0] = (a0[0] >> 16) | (a0[1] & 0xFFFF0000u);
        pk[1] = (a0[2] >> 16) | (a0[3] & 0xFFFF0000u);
        pk[2] = (a1[0] >> 16) | (a1[1] & 0xFFFF0000u);
        pk[3] = (a1[2] >> 16) | (a1[3] & 0xFFFF0000u);
        *(u32x4*)&As[m][(c ^ ((m >> 1) & 3))*8] = pk;
      }
    }
    __syncthreads();
    bf8v af[4], bf[4];
    #pragma unroll
    for (int mt = 0; mt < 4; ++mt) af[mt] = *(const bf8v*)&As[wm*64 + mt*16 + l15][poff];
    #pragma unroll
    for (int nt = 0; nt < 4; ++nt) bf[nt] = *(const bf8v*)&Bs[wn*64 + nt*16 + l15][poff];
    #pragma unroll
    for (int mt = 0; mt < 4; ++mt)
      #pragma unroll
      for (int nt = 0; nt < 4; ++nt)
        acc[mt][nt] = __builtin_amdgcn_mfma_f32_16x16x32_bf16(af[mt], bf[nt], acc[mt][nt], 0, 0, 0);
  }

  #pragma unroll
  for (int mt = 0; mt < 4; ++mt)
    #pragma unroll
    for (int nt = 0; nt < 4; ++nt)
      #pragma unroll
      for (int reg = 0; reg < 4; ++reg){
        int grow = bm*128 + wm*64 + mt*16 + quad*4 + reg;
        int gcol = bn*128 + wn*64 + nt*16 + l15;
        Cv[(size_t)grow*ldc + gcol] = f2b(acc[mt][nt][reg]);
      }
}

// fused projections: tiles 0..383 = A1@wq|wkv -> qkvh (4096x1536); 384..767 = A2@wr -> krh (8192x768)
__global__ __launch_bounds__(256) void gemm_proj(const void* __restrict__ A1, const void* __restrict__ A2,
                                                 const u16* __restrict__ wqkv,
                                                 u16* __restrict__ qkvh, u16* __restrict__ krh, int amode){
  __shared__ u16 As[128][32];
  __shared__ u16 Bs[128][32];
  int t = blockIdx.x;
  if (t < 384){
    if (amode) gemm_core<2>(A1, 768, wqkv, qkvh, 1536, t & 31, t >> 5, As, Bs);
    else       gemm_core<0>(A1, 768, wqkv, qkvh, 1536, t & 31, t >> 5, As, Bs);
  } else {
    t -= 384;
    if (amode) gemm_core<2>(A2, 768, wqkv + 2*768*768, krh, 768, t & 63, t >> 6, As, Bs);
    else       gemm_core<0>(A2, 768, wqkv + 2*768*768, krh, 768, t & 63, t >> 6, As, Bs);
  }
}

// ---------------- out-proj: 64x64 tiles, grid (64,12) = 768 blocks ----------------
// C = gelu(ctx @ woutT + bias + resid), fp32 out. 4 waves 2x2 of 32x32; GLDS both operands.
__global__ __launch_bounds__(256) void gemm_out(const u16* __restrict__ ctx, const u16* __restrict__ wout,
                                                float* __restrict__ out,
                                                const float* __restrict__ resid, const float* __restrict__ bias){
  __shared__ u16 As[64][32];
  __shared__ u16 Bs[64][32];
  int tid = threadIdx.x;
  int lane = tid & 63, rg = tid >> 6;
  int quad = lane >> 4, l15 = lane & 15;
  int wm = rg >> 1, wn = rg & 1;
  int bm = blockIdx.x, bn = blockIdx.y;
  f32x4 acc[2][2];
  #pragma unroll
  for (int i = 0; i < 2; ++i)
    #pragma unroll
    for (int j = 0; j < 2; ++j)
      acc[i][j] = (f32x4){0.f,0.f,0.f,0.f};

  int m = tid >> 2, s = (tid & 3)*8;
  for (int kt = 0; kt < 24; ++kt){
    int k0 = kt*32;
    if (kt) __syncthreads();
    GLDS16(&ctx[(size_t)(bm*64 + m)*768 + k0 + s], &As[m][s]);
    GLDS16(&wout[(size_t)(bn*64 + m)*768 + k0 + s], &Bs[m][s]);
    __syncthreads();
    bf8v af[2], bf[2];
    #pragma unroll
    for (int mt = 0; mt < 2; ++mt) af[mt] = *(const bf8v*)&As[wm*32 + mt*16 + l15][quad*8];
    #pragma unroll
    for (int nt = 0; nt < 2; ++nt) bf[nt] = *(const bf8v*)&Bs[wn*32 + nt*16 + l15][quad*8];
    #pragma unroll
    for (int mt = 0; mt < 2; ++mt)
      #pragma unroll
      for (int nt = 0; nt < 2; ++nt)
        acc[mt][nt] = __builtin_amdgcn_mfma_f32_16x16x32_bf16(af[mt], bf[nt], acc[mt][nt], 0, 0, 0);
  }

  #pragma unroll
  for (int mt = 0; mt < 2; ++mt)
    #pragma unroll
    for (int nt = 0; nt < 2; ++nt)
      #pragma unroll
      for (int reg = 0; reg < 4; ++reg){
        int grow = bm*64 + wm*32 + mt*16 + quad*4 + reg;
        int gcol = bn*64 + wn*32 + nt*16 + l15;
        float v = acc[mt][nt][reg] + bias[gcol] + resid[(size_t)grow*768 + gcol];
        v = 0.5f * v * (1.0f + erff(v * 0.70710678118654752f));
        out[(size_t)grow*768 + gcol] = v;
      }
}

// ---------------- fused rel-pos flash attention: 32-row Q-tile, GLDS staging ----------------
// kvL[64][64] unpadded, granule-rotated: logical granule G of row k stored at (G+2*(k>>3))&7.
// krL[96][64] rotated by 3*(jj>>3). Both staged via global_load_lds w=16.
// qw/qr in padded qL[2][32][72]; scores computed in log2 domain (q pre-scaled by 0.125*log2e,
// exp2f = v_exp_f32 directly). Mask via per-kt transposed u32 word (coalesced global load, bit per
// Q-row for this lane's key) -> select-zero after exp. rel-shift band shuffled as ONE
// ds_bpermute of a cvt_pkrtz f16 pair (halves shuffle LDS ops). kv/kr B-fragments dedup'd across
// row-groups (kB band shared by rgi0.bd0/rgi1.bd1) -> 8 b128 reads instead of 12.
__global__ __launch_bounds__(256, 4) void attn(const u16* __restrict__ qkvh,
                                               const u16* __restrict__ krh,
                                               const u32* __restrict__ mbT,
                                               const float* __restrict__ rrb,
                                               const float* __restrict__ rwb,
                                               const u16* __restrict__ zp,
                                               u16* __restrict__ ctx){
  __shared__ u16 kvL[64][64];
  __shared__ u16 krL[96][64];
  __shared__ u16 qL[2][32][72];
  __shared__ u16 pL[32][72];
  __shared__ float lpart[4][32];

  int tid = threadIdx.x;
  int lane = tid & 63, w = tid >> 6;
  int quad = lane >> 4, l15 = lane & 15;

  // XCD swizzle: blocks sharing (b,n) land on one XCD's L2
  int fid = blockIdx.x;                // 0..1535
  int xcd = fid & 7, loc = fid >> 3;
  int pair = xcd*6 + (loc >> 5);
  int i0 = (loc & 31) * 32;
  int b = pair / 12, n = pair % 12;

  const u16* kvbase = qkvh + (size_t)b*S_*1536 + 768 + n*64;
  const u16* krbase = krh + (size_t)b*POS_*768 + n*64;
  const float SC = 0.18033688f;        // 0.125 * log2(e): scores in log2 domain

  // stage qw/qr (32 rows x 64 d), pre-scaled
  {
    int r = tid >> 3, d0 = (tid & 7)*8;
    bf8v qv = *(const bf8v*)&qkvh[(size_t)(b*S_ + i0 + r)*1536 + n*64 + d0];
    f32x4 w0 = *(const f32x4*)&rwb[n*64 + d0];
    f32x4 w1 = *(const f32x4*)&rwb[n*64 + d0 + 4];
    f32x4 r0 = *(const f32x4*)&rrb[n*64 + d0];
    f32x4 r1 = *(const f32x4*)&rrb[n*64 + d0 + 4];
    bf8v qw, qr;
    #pragma unroll
    for (int j = 0; j < 4; ++j){
      float qf0 = b2f((u16)qv[j]), qf1 = b2f((u16)qv[4+j]);
      qw[j]   = f2b((qf0 + w0[j])*SC);
      qw[4+j] = f2b((qf1 + w1[j])*SC);
      qr[j]   = f2b((qf0 + r0[j])*SC);
      qr[4+j] = f2b((qf1 + r1[j])*SC);
    }
    *(bf8v*)&qL[0][r][d0] = qw;
    *(bf8v*)&qL[1][r][d0] = qr;
  }
  __syncthreads();
  bf8v qwf[2][2], qrf[2][2];
  #pragma unroll
  for (int rgi = 0; rgi < 2; ++rgi)
    #pragma unroll
    for (int c = 0; c < 2; ++c){
      qwf[rgi][c] = *(const bf8v*)&qL[0][rgi*16 + l15][c*32 + quad*8];
      qrf[rgi][c] = *(const bf8v*)&qL[1][rgi*16 + l15][c*32 + quad*8];
    }

  f32x4 ctxa[2];
  float l_acc[2][4];
  #pragma unroll
  for (int i = 0; i < 2; ++i){
    ctxa[i] = (f32x4){0.f,0.f,0.f,0.f};
    #pragma unroll
    for (int j = 0; j < 4; ++j) l_acc[i][j] = 0.f;
  }

  int key = w*16 + l15;
  int pvcol = (((key >> 3) + 2*quad) & 7)*8 + (key & 7);   // PV gather col (c-independent)
  const u32* mrowp = mbT + ((size_t)(b*32 + (i0 >> 5))*16)*64 + key;

  for (int kt = 0; kt < 16; ++kt){
    int k0 = kt*64;
    int j0 = k0 + S_ - i0 - 31;          // >= 1 always
    __syncthreads();                     // prev-tile consumers done
    // kvL via GLDS (2/lane): slot [k][s*8] <- global granule g = (s - 2*(k>>3)) & 7
    #pragma unroll
    for (int e = 0; e < 2; ++e){
      int v = tid + 256*e;
      int k = v >> 3, s = v & 7;
      int g = (s - 2*(k >> 3)) & 7;
      GLDS16(&kvbase[(size_t)(k0 + k)*1536 + g*8], &kvL[k][s*8]);
    }
    // krL via GLDS (3/lane): slot [jj][s*8] <- granule g = (s - 3*(jj>>3)) & 7; OOB -> zero patch
    #pragma unroll
    for (int e = 0; e < 3; ++e){
      int v = tid + 256*e;
      int jj = v >> 3, s = v & 7;
      int g = (s - 3*(jj >> 3)) & 7;
      int jg = j0 + jj;
      const u16* src = (jg < POS_) ? &krbase[(size_t)jg*768 + g*8] : zp;
      GLDS16(src, &krL[jj][s*8]);
    }
    u32 mrow = mrowp[(size_t)kt*64];     // transposed mask word: bit r = masked(row i0+r, this key)
    __syncthreads();

    // ---- QK phase: dedup'd B-fragment reads ----
    int rA = w*16 + l15;                 // rgi1 bd0 rows; rB=rA+16 shared; rC=rA+32 rgi0 bd1
    f32x4 ac0 = (f32x4){0.f,0.f,0.f,0.f}, ac1 = (f32x4){0.f,0.f,0.f,0.f};
    f32x4 b00 = (f32x4){0.f,0.f,0.f,0.f}, b01 = (f32x4){0.f,0.f,0.f,0.f};
    f32x4 b10 = (f32x4){0.f,0.f,0.f,0.f}, b11 = (f32x4){0.f,0.f,0.f,0.f};
    #pragma unroll
    for (int c = 0; c < 2; ++c){
      int p = (c*4 + quad + 2*(key >> 3)) & 7;
      bf8v bkv = *(const bf8v*)&kvL[key][p*8];
      ac0 = __builtin_amdgcn_mfma_f32_16x16x32_bf16(qwf[0][c], bkv, ac0, 0, 0, 0);
      ac1 = __builtin_amdgcn_mfma_f32_16x16x32_bf16(qwf[1][c], bkv, ac1, 0, 0, 0);
    }
    #pragma unroll
    for (int c = 0; c < 2; ++c){
      int rB = rA + 16;
      bf8v kB = *(const bf8v*)&krL[rB][((c*4 + quad + 3*(rB >> 3)) & 7)*8];
      b00 = __builtin_amdgcn_mfma_f32_16x16x32_bf16(qrf[0][c], kB, b00, 0, 0, 0);
      b11 = __builtin_amdgcn_mfma_f32_16x16x32_bf16(qrf[1][c], kB, b11, 0, 0, 0);
    }
    #pragma unroll
    for (int c = 0; c < 2; ++c){
      int rC = rA + 32;
      bf8v kC = *(const bf8v*)&krL[rC][((c*4 + quad + 3*(rC >> 3)) & 7)*8];
      b01 = __builtin_amdgcn_mfma_f32_16x16x32_bf16(qrf[0][c], kC, b01, 0, 0, 0);
    }
    #pragma unroll
    for (int c = 0; c < 2; ++c){
      bf8v kA = *(const bf8v*)&krL[rA][((c*4 + quad + 3*(rA >> 3)) & 7)*8];
      b10 = __builtin_amdgcn_mfma_f32_16x16x32_bf16(qrf[1][c], kA, b10, 0, 0, 0);
    }

    // ---- softmax: pack band pair to f16, single bpermute, exp2, mask->0 ----
    f32x4 acA[2]  = {ac0, ac1};
    f32x4 bdLo[2] = {b00, b10};
    f32x4 bdHi[2] = {b01, b11};
    #pragma unroll
    for (int rgi = 0; rgi < 2; ++rgi){
      u32 mq = mrow >> (rgi*16 + quad*4);
      u32 pk_[4];
      #pragma unroll
      for (int reg = 0; reg < 4; ++reg){
        union { fp16x2 h; u32 u; } cv;
        cv.h = __builtin_amdgcn_cvt_pkrtz(bdLo[rgi][reg], bdHi[rgi][reg]);
        pk_[reg] = cv.u;
      }
      #pragma unroll
      for (int reg = 0; reg < 4; ++reg){
        int sj = l15 + 15 - (quad*4 + reg);
        int srcl = (sj & 15) | (lane & 48);
        u32 got = (u32)__builtin_amdgcn_ds_bpermute(srcl << 2, (int)pk_[reg]);
        union { u16 s; __fp16 h; } hv;
        hv.s = (u16)(got >> (sj & 16));  // lo half = bd0, hi half = bd1
        float sc = acA[rgi][reg] + (float)hv.h;
        float e = exp2f(sc);             // 2^sc == e^score (log2e folded into SC)
        float p = ((mq >> reg) & 1u) ? 0.0f : e;
        l_acc[rgi][reg] += p;
        pL[rgi*16 + quad*4 + reg][key] = f2bt(p);
      }
    }
    __syncthreads();

    // PV: column gather (2 lanes/bank), shared across row-groups
    bf8v bv[2];
    #pragma unroll
    for (int c = 0; c < 2; ++c)
      #pragma unroll
      for (int j = 0; j < 8; ++j)
        bv[c][j] = (short)kvL[c*32 + quad*8 + j][pvcol];
    #pragma unroll
    for (int rgi = 0; rgi < 2; ++rgi)
      #pragma unroll
      for (int c = 0; c < 2; ++c){
        bf8v pa = *(const bf8v*)&pL[rgi*16 + l15][c*32 + quad*8];
        ctxa[rgi] = __builtin_amdgcn_mfma_f32_16x16x32_bf16(pa, bv[c], ctxa[rgi], 0, 0, 0);
      }
  }

  // l reduction
  #pragma unroll
  for (int rgi = 0; rgi < 2; ++rgi)
    #pragma unroll
    for (int reg = 0; reg < 4; ++reg){
      float v = l_acc[rgi][reg];
      #pragma unroll
      for (int off = 1; off < 16; off <<= 1) v += __shfl_xor(v, off);
      l_acc[rgi][reg] = v;
    }
  if (l15 == 0){
    #pragma unroll
    for (int rgi = 0; rgi < 2; ++rgi)
      #pragma unroll
      for (int reg = 0; reg < 4; ++reg)
        lpart[w][rgi*16 + quad*4 + reg] = l_acc[rgi][reg];
  }
  __syncthreads();
  #pragma unroll
  for (int rgi = 0; rgi < 2; ++rgi)
    #pragma unroll
    for (int reg = 0; reg < 4; ++reg){
      int rloc = rgi*16 + quad*4 + reg;
      float lt = lpart[0][rloc] + lpart[1][rloc] + lpart[2][rloc] + lpart[3][rloc];
      ctx[(size_t)(b*S_ + i0 + rloc)*768 + n*64 + w*16 + l15] = f2b(ctxa[rgi][reg] / lt);
    }
}

// ---------------- launch ----------------
extern "C" void kernel_launch(void* const* d_in, const int* in_sizes, int n_in,
                              void* d_out, int out_size, void* d_ws, size_t ws_size,
                              hipStream_t stream){
  (void)in_sizes; (void)n_in; (void)out_size;
  const float* hidden = (const float*)d_in[0];
  const float* pos    = (const float*)d_in[1];
  const float* maskp  = (const float*)d_in[2];
  const float* q      = (const float*)d_in[3];
  const float* kv     = (const float*)d_in[4];
  const float* r      = (const float*)d_in[5];
  const float* rrb    = (const float*)d_in[6];
  const float* rwb    = (const float*)d_in[7];
  const float* wo     = (const float*)d_in[8];
  const float* bo     = (const float*)d_in[9];
  float* out = (float*)d_out;

  // ws (u16 units): qkvh | krh | wout | wqkv | [big: hb | pb] | mbT(u32, 512KB) | zp
  u16* qkvh = (u16*)d_ws;
  u16* krh  = qkvh + (size_t)4096*1536;
  u16* wout = krh  + (size_t)8192*768;
  u16* wqkv = wout + 768*768;
  bool big = ws_size >= 49283104ull;
  u16 *hb = nullptr, *pb = nullptr, *ctx;
  u64* mbp;
  if (big){
    hb  = wqkv + (size_t)3*768*768;
    pb  = hb + (size_t)4096*768;
    ctx = hb;
    mbp = (u64*)(pb + (size_t)8192*768);
  } else {
    ctx = wqkv;
    mbp = (u64*)(wqkv + (size_t)4096*768);
  }
  u16* zp = (u16*)(mbp + 65536);

  prep<<<dim3(big ? 7424 : 2816), 256, 0, stream>>>(q, kv, r, wo, wqkv, wout,
                                                    maskp, (u32*)mbp, zp, hidden, pos, hb, pb);
  if (big) gemm_proj<<<dim3(768), 256, 0, stream>>>(hb, pb, wqkv, qkvh, krh, 2);
  else     gemm_proj<<<dim3(768), 256, 0, stream>>>(hidden, pos, wqkv, qkvh, krh, 0);
  attn<<<dim3(1536), 256, 0, stream>>>(qkvh, krh, (const u32*)mbp, rrb, rwb, zp, ctx);
  gemm_out<<<dim3(64,12), 256, 0, stream>>>(ctx, wout, out, hidden, bo);
}